// Round 1
// baseline (1073.677 us; speedup 1.0000x reference)
//
#include <hip/hip_runtime.h>
#include <hip/hip_fp16.h>

typedef _Float16 f16;
typedef _Float16 f16x8 __attribute__((ext_vector_type(8)));
typedef float f32x4 __attribute__((ext_vector_type(4)));
typedef float f32x2 __attribute__((ext_vector_type(2)));

#define HDIM 128
#define LAYERS 4
#define NEG_BIG (-3.0e38f)

static __device__ __forceinline__ f32x4 mfma16(f16x8 a, f16x8 b, f32x4 c) {
  return __builtin_amdgcn_mfma_f32_16x16x32_f16(a, b, c, 0, 0, 0);
}

// ---------------- CSR build ----------------
__global__ void gnn_hist(const int* __restrict__ ei, int* __restrict__ deg, int E) {
  int e = blockIdx.x * 256 + threadIdx.x;
  if (e < E) atomicAdd(&deg[ei[E + e]], 1);
}

__global__ void gnn_scan(const int* __restrict__ deg, int* __restrict__ offs,
                         int* __restrict__ cursor, int N) {
  __shared__ int sums[1024];
  int tid = threadIdx.x;
  int chunk = (N + 1023) / 1024;
  int s0 = tid * chunk;
  int s1 = s0 + chunk; if (s1 > N) s1 = N; if (s0 > N) s0 = N;
  int s = 0;
  for (int i = s0; i < s1; i++) s += deg[i];
  sums[tid] = s;
  __syncthreads();
  for (int d = 1; d < 1024; d <<= 1) {
    int add = (tid >= d) ? sums[tid - d] : 0;
    __syncthreads();
    sums[tid] += add;
    __syncthreads();
  }
  int run = (tid > 0) ? sums[tid - 1] : 0;
  for (int i = s0; i < s1; i++) {
    offs[i] = run; cursor[i] = run;
    run += deg[i];
  }
  if (tid == 1023) offs[N] = sums[1023];
}

__global__ void gnn_scatter(const int* __restrict__ ei, int* __restrict__ cursor,
                            int* __restrict__ colsrc, int E) {
  int e = blockIdx.x * 256 + threadIdx.x;
  if (e < E) {
    int d = ei[E + e];
    int p = atomicAdd(&cursor[d], 1);
    colsrc[p] = ei[e];
  }
}

// ---------------- weight prep: fragment-ordered f16 hi/lo planes ----------------
// Wc: per layer [plane(2)][kk(4)][ntile(16)][lane(64)][j(8)]   (cols 0..127 = W1a-W1b (P), 128..255 = W1b (Q))
__global__ void gnn_wprep1(const float* __restrict__ W1, f16* __restrict__ Wc) {
  int id = blockIdx.x * 256 + threadIdx.x;
  if (id >= LAYERS * 128 * 256) return;
  int col = id & 255, k = (id >> 8) & 127, l = id >> 15;
  float w;
  if (col < 128) w = W1[((size_t)l * 256 + k) * 128 + col] - W1[((size_t)l * 256 + 128 + k) * 128 + col];
  else           w = W1[((size_t)l * 256 + 128 + k) * 128 + (col - 128)];
  f16 hi = (f16)w;
  f16 lo = (f16)(w - (float)hi);
  int kk = k >> 5, quad = (k >> 3) & 3, j = k & 7;
  int ntile = col >> 4, lane = quad * 16 + (col & 15);
  size_t base = ((((size_t)l * 2 + 0) * 4 + kk) * 16 + ntile) * 512 + lane * 8 + j;
  Wc[base] = hi;
  Wc[base + (size_t)4 * 16 * 512] = lo;  // plane 1
}

// W2f: per layer [plane(2)][kk(4)][ntile(8)][lane(64)][j(8)]
__global__ void gnn_wprep2(const float* __restrict__ W2, f16* __restrict__ W2f) {
  int id = blockIdx.x * 256 + threadIdx.x;
  if (id >= LAYERS * 128 * 128) return;
  int n = id & 127, k = (id >> 7) & 127, l = id >> 14;
  float w = W2[((size_t)l * 128 + k) * 128 + n];
  f16 hi = (f16)w;
  f16 lo = (f16)(w - (float)hi);
  int kk = k >> 5, quad = (k >> 3) & 3, j = k & 7;
  int ntile = n >> 4, lane = quad * 16 + (n & 15);
  size_t base = ((((size_t)l * 2 + 0) * 4 + kk) * 8 + ntile) * 512 + lane * 8 + j;
  W2f[base] = hi;
  W2f[base + (size_t)4 * 8 * 512] = lo;  // plane 1
}

// ---------------- per-layer node GEMM: P = x@(W1a-W1b)+b1, Q = x@W1b ----------------
// block: 256 thr, 64 rows x 256 cols, K=128, 3-term f16 split (fp32-accurate)
__global__ __launch_bounds__(256) void gnn_pq(const float* __restrict__ x,
    const f16* __restrict__ Wc, const float* __restrict__ b1,
    float* __restrict__ P, float* __restrict__ Q, int N) {
  __shared__ __align__(16) f16 shA[2 * 4 * 4 * 64 * 8];  // [plane][kk][mt][lane][8] = 32KB
  int tid = threadIdx.x;
  int row0 = blockIdx.x * 64;
#pragma unroll
  for (int i = 0; i < 4; i++) {
    int p = i * 256 + tid;
    int row = p & 63, seg = p >> 6;
    float v[8];
    int gr = row0 + row;
    if (gr < N) {
      const f32x4* xp = (const f32x4*)(x + (size_t)gr * HDIM + seg * 8);
      f32x4 a = xp[0], b = xp[1];
      v[0]=a.x; v[1]=a.y; v[2]=a.z; v[3]=a.w; v[4]=b.x; v[5]=b.y; v[6]=b.z; v[7]=b.w;
    } else {
#pragma unroll
      for (int j = 0; j < 8; j++) v[j] = 0.f;
    }
    f16x8 hv, lv;
#pragma unroll
    for (int j = 0; j < 8; j++) { f16 h = (f16)v[j]; hv[j] = h; lv[j] = (f16)(v[j] - (float)h); }
    int kk = seg >> 2, quad = seg & 3, mt = row >> 4, m = row & 15;
    int lane = quad * 16 + m;
    int off = ((kk * 4 + mt) * 64 + lane) * 8;
    *(f16x8*)&shA[off] = hv;
    *(f16x8*)&shA[off + 4 * 4 * 64 * 8] = lv;
  }
  __syncthreads();
  int wave = tid >> 6, lane = tid & 63;
  int quad = lane >> 4, cl = lane & 15;
  f16x8 bw[2][4][4];  // [plane][nt][kk]
#pragma unroll
  for (int pl = 0; pl < 2; pl++)
#pragma unroll
    for (int nt = 0; nt < 4; nt++)
#pragma unroll
      for (int kk = 0; kk < 4; kk++) {
        int ntile = wave * 4 + nt;
        bw[pl][nt][kk] = *(const f16x8*)&Wc[(((size_t)(pl * 4 + kk) * 16 + ntile) * 64 + lane) * 8];
      }
#pragma unroll
  for (int mt = 0; mt < 4; mt++) {
    f32x4 acc[4] = {};
#pragma unroll
    for (int kk = 0; kk < 4; kk++) {
      f16x8 ah = *(const f16x8*)&shA[((kk * 4 + mt) * 64 + lane) * 8];
      f16x8 al = *(const f16x8*)&shA[(((4 + kk) * 4 + mt) * 64 + lane) * 8];
#pragma unroll
      for (int nt = 0; nt < 4; nt++) {
        acc[nt] = mfma16(ah, bw[0][nt][kk], acc[nt]);
        acc[nt] = mfma16(al, bw[0][nt][kk], acc[nt]);
        acc[nt] = mfma16(ah, bw[1][nt][kk], acc[nt]);
      }
    }
#pragma unroll
    for (int nt = 0; nt < 4; nt++) {
      int c = (wave * 4 + nt) * 16 + cl;
      float bb = (c < HDIM) ? b1[c] : 0.f;
      float* dst = (c < HDIM) ? P : Q;
      int cc = c & 127;
#pragma unroll
      for (int i = 0; i < 4; i++) {
        int gr = row0 + mt * 16 + quad * 4 + i;
        if (gr < N) dst[(size_t)gr * HDIM + cc] = acc[nt][i] + bb;
      }
    }
  }
}

// ---------------- per-edge MLP + segment max ----------------
// block: 256 thr (4 waves), owns nodes [v0,v1). 16-edge chunks, M=16 MFMA,
// wave w -> cols [w*32, w*32+32). Running max in regs, one store per node row.
__global__ __launch_bounds__(256) void gnn_edge(const float* __restrict__ P,
    const float* __restrict__ Q, const int* __restrict__ offs,
    const int* __restrict__ colsrc, const f16* __restrict__ W2f,
    const float* __restrict__ b2, float* __restrict__ xout, int N, int npb) {
  __shared__ __align__(16) f16 shA[2 * 2 * 4 * 64 * 8];  // [buf][plane][kk][lane][8] = 16KB
  __shared__ float pf[HDIM];
  int tid = threadIdx.x;
  int wave = tid >> 6, lane = tid & 63;
  int quad = lane >> 4, cl = lane & 15;
  int r = tid & 15, seg = tid >> 4;  // builder coords; kk-slice written = wave
  f16x8 bw[2][2][4];  // [plane][nt][kk]
#pragma unroll
  for (int pl = 0; pl < 2; pl++)
#pragma unroll
    for (int nt = 0; nt < 2; nt++)
#pragma unroll
      for (int kk = 0; kk < 4; kk++)
        bw[pl][nt][kk] = *(const f16x8*)&W2f[(((size_t)(pl * 4 + kk) * 8 + (wave * 2 + nt)) * 64 + lane) * 8];
  float b2v0 = b2[wave * 32 + cl];
  float b2v1 = b2[wave * 32 + 16 + cl];
  int v0 = blockIdx.x * npb;
  int v1 = v0 + npb; if (v1 > N) v1 = N;
  int bufc = 0;
  for (int v = v0; v < v1; v++) {
    int ebase = offs[v];
    int dtot = 1 + (offs[v + 1] - ebase);  // self-loop is slot 0
    if (tid < HDIM) pf[tid] = P[(size_t)v * HDIM + tid];
    __syncthreads();
    int nch = (dtot + 15) >> 4;
    f32x4 rm0, rm1;
#pragma unroll
    for (int i = 0; i < 4; i++) { rm0[i] = NEG_BIG; rm1[i] = NEG_BIG; }
    for (int ch = 0; ch < nch; ch++) {
      int buf = bufc & 1; bufc++;
      int slot = ch * 16 + r;
      int src = (slot == 0) ? v : ((slot < dtot) ? colsrc[ebase + slot - 1] : -1);
      f16x8 hv = {}, lv = {};
      if (src >= 0) {
        const f32x4* qp = (const f32x4*)(Q + (size_t)src * HDIM + seg * 8);
        f32x4 qa = qp[0], qb = qp[1];
        float q[8] = {qa.x, qa.y, qa.z, qa.w, qb.x, qb.y, qb.z, qb.w};
#pragma unroll
        for (int j = 0; j < 8; j++) {
          float pre = pf[seg * 8 + j] + q[j];
          pre = fmaxf(pre, 0.f);
          f16 h = (f16)pre; hv[j] = h; lv[j] = (f16)(pre - (float)h);
        }
      }
      int wo = ((buf * 2 + 0) * 4 + wave) * 512 + lane * 8;
      *(f16x8*)&shA[wo] = hv;
      *(f16x8*)&shA[wo + 4 * 512] = lv;
      __syncthreads();
      f32x4 a0 = {}, a1 = {};
#pragma unroll
      for (int kk = 0; kk < 4; kk++) {
        f16x8 ah = *(const f16x8*)&shA[((buf * 2 + 0) * 4 + kk) * 512 + lane * 8];
        f16x8 al = *(const f16x8*)&shA[((buf * 2 + 1) * 4 + kk) * 512 + lane * 8];
        a0 = mfma16(ah, bw[0][0][kk], a0);
        a0 = mfma16(al, bw[0][0][kk], a0);
        a0 = mfma16(ah, bw[1][0][kk], a0);
        a1 = mfma16(ah, bw[0][1][kk], a1);
        a1 = mfma16(al, bw[0][1][kk], a1);
        a1 = mfma16(ah, bw[1][1][kk], a1);
      }
      int rem = dtot - ch * 16;  // valid rows in this chunk (>=1)
#pragma unroll
      for (int i = 0; i < 4; i++) {
        bool ok = (quad * 4 + i) < rem;
        rm0[i] = fmaxf(rm0[i], ok ? a0[i] : NEG_BIG);
        rm1[i] = fmaxf(rm1[i], ok ? a1[i] : NEG_BIG);
      }
    }
    float m0 = fmaxf(fmaxf(rm0[0], rm0[1]), fmaxf(rm0[2], rm0[3]));
    float m1 = fmaxf(fmaxf(rm1[0], rm1[1]), fmaxf(rm1[2], rm1[3]));
    m0 = fmaxf(m0, __shfl_xor(m0, 16, 64));
    m0 = fmaxf(m0, __shfl_xor(m0, 32, 64));
    m1 = fmaxf(m1, __shfl_xor(m1, 16, 64));
    m1 = fmaxf(m1, __shfl_xor(m1, 32, 64));
    if (quad == 0) {
      xout[(size_t)v * HDIM + wave * 32 + cl] = m0 + b2v0;
      xout[(size_t)v * HDIM + wave * 32 + 16 + cl] = m1 + b2v1;
    }
    // pf overwrite for v+1 is safe: all pf reads precede the last chunk barrier
  }
}

// ---------------- final fc: out = x @ Wf + bf ----------------
__global__ __launch_bounds__(256) void gnn_fc(const float* __restrict__ x,
    const float* __restrict__ Wf, const float* __restrict__ bfv,
    float* __restrict__ out, int N) {
  int wave = threadIdx.x >> 6, lane = threadIdx.x & 63;
  int wid = blockIdx.x * 4 + wave, nw = gridDim.x * 4;
  int k0 = lane * 2;
  float w00 = Wf[k0 * 3 + 0], w01 = Wf[k0 * 3 + 1], w02 = Wf[k0 * 3 + 2];
  float w10 = Wf[k0 * 3 + 3], w11 = Wf[k0 * 3 + 4], w12 = Wf[k0 * 3 + 5];
  float bf0 = bfv[0], bf1 = bfv[1], bf2 = bfv[2];
  for (int v = wid; v < N; v += nw) {
    f32x2 xx = *(const f32x2*)(x + (size_t)v * HDIM + k0);
    float d0 = xx.x * w00 + xx.y * w10;
    float d1 = xx.x * w01 + xx.y * w11;
    float d2 = xx.x * w02 + xx.y * w12;
#pragma unroll
    for (int s = 32; s; s >>= 1) {
      d0 += __shfl_xor(d0, s, 64);
      d1 += __shfl_xor(d1, s, 64);
      d2 += __shfl_xor(d2, s, 64);
    }
    if (lane == 0) {
      out[(size_t)v * 3 + 0] = d0 + bf0;
      out[(size_t)v * 3 + 1] = d1 + bf1;
      out[(size_t)v * 3 + 2] = d2 + bf2;
    }
  }
}

extern "C" void kernel_launch(void* const* d_in, const int* in_sizes, int n_in,
                              void* d_out, int out_size, void* d_ws, size_t ws_size,
                              hipStream_t stream) {
  const float* x_in = (const float*)d_in[0];
  const int*   ei   = (const int*)d_in[1];
  const float* W1   = (const float*)d_in[2];
  const float* b1   = (const float*)d_in[3];
  const float* W2   = (const float*)d_in[4];
  const float* b2   = (const float*)d_in[5];
  const float* Wf   = (const float*)d_in[6];
  const float* bfv  = (const float*)d_in[7];
  float* outp = (float*)d_out;
  int N = in_sizes[0] / HDIM;
  int E = in_sizes[1] / 2;

  char* ws = (char*)d_ws;
  size_t o = 0;
  auto alloc = [&](size_t bytes) -> char* {
    char* p = ws + o;
    o += (bytes + 255) & ~(size_t)255;
    return p;
  };
  int*   deg    = (int*)alloc((size_t)N * 4);
  int*   offs   = (int*)alloc(((size_t)N + 1) * 4);
  int*   cursor = (int*)alloc((size_t)N * 4);
  int*   colsrc = (int*)alloc((size_t)E * 4);
  float* P      = (float*)alloc((size_t)N * HDIM * 4);
  float* Q      = (float*)alloc((size_t)N * HDIM * 4);
  float* xbuf   = (float*)alloc((size_t)N * HDIM * 4);
  f16*   Wc     = (f16*)alloc((size_t)LAYERS * 65536 * 2);
  f16*   W2f    = (f16*)alloc((size_t)LAYERS * 32768 * 2);
  (void)ws_size; (void)n_in; (void)out_size;

  hipMemsetAsync(deg, 0, (size_t)N * 4, stream);
  gnn_hist<<<(E + 255) / 256, 256, 0, stream>>>(ei, deg, E);
  gnn_scan<<<1, 1024, 0, stream>>>(deg, offs, cursor, N);
  gnn_scatter<<<(E + 255) / 256, 256, 0, stream>>>(ei, cursor, colsrc, E);
  gnn_wprep1<<<(LAYERS * 128 * 256 + 255) / 256, 256, 0, stream>>>(W1, Wc);
  gnn_wprep2<<<(LAYERS * 128 * 128 + 255) / 256, 256, 0, stream>>>(W2, W2f);

  const int GE = 2048;
  int npb = (N + GE - 1) / GE;
  const float* xc = x_in;
  for (int l = 0; l < LAYERS; l++) {
    gnn_pq<<<(N + 63) / 64, 256, 0, stream>>>(xc, Wc + (size_t)l * 65536, b1 + (size_t)l * HDIM, P, Q, N);
    gnn_edge<<<GE, 256, 0, stream>>>(P, Q, offs, colsrc, W2f + (size_t)l * 32768, b2 + (size_t)l * HDIM, xbuf, N, npb);
    xc = xbuf;
  }
  gnn_fc<<<256, 256, 0, stream>>>(xc, Wf, bfv, outp, N);
}